// Round 1
// baseline (8980.259 us; speedup 1.0000x reference)
//
#include <hip/hip_runtime.h>
#include <hip/hip_bf16.h>

// Problem constants (fixed by the reference)
#define T_STEPS 1024
#define B_SZ 256
#define D_SZ 256
#define U_SZ 512
#define O_SZ 256
#define K_TOT 768            // D + U concatenated K

// Partition: 16 row-groups x 16 col-groups = 256 wgs (1 per CU)
#define ROWS_PER_WG 16       // batch rows per wg == MFMA M
#define COLS_PER_WG 32       // U columns per wg (2 waves x N=16)
#define GROUPS 16            // row groups (barrier groups)
#define COLGRPS 16           // members per barrier group
#define WT_PITCH 776         // 768 + 8 shorts pad (pitch 1552B: 4-bank skew, 16B aligned)
#define CTR_PITCH 1056       // counter slots per group (>= T+1), 128B-multiple pitch

typedef __attribute__((ext_vector_type(8))) short short8;   // MFMA bf16 A/B frag (4 VGPRs)
typedef __attribute__((ext_vector_type(4))) float floatx4;  // MFMA fp32 C/D frag
typedef __attribute__((ext_vector_type(4))) unsigned int uint4v;

__device__ __forceinline__ unsigned short f2bf(float f) {
  union { float f; unsigned int u; } v; v.f = f;
  unsigned int r = v.u + 0x7FFFu + ((v.u >> 16) & 1u);  // RNE
  return (unsigned short)(r >> 16);
}
__device__ __forceinline__ float bf2f(unsigned short s) {
  union { unsigned int u; float f; } v; v.u = ((unsigned int)s) << 16;
  return v.f;
}
// packed 2x f32 -> 2x bf16 (RNE); uses HW cvt_pk on gfx950 via the hip header
__device__ __forceinline__ unsigned int pk2(float a, float b) {
  union { __hip_bfloat162 h; unsigned int u; } cv;
  cv.h = __float22bfloat162_rn(make_float2(a, b));  // low16 = a, high16 = b
  return cv.u;
}

// Persistent RNN kernel. Each wg: rows [16g,16g+16), cols [32c,32c+32).
// W-slice lives in LDS for all T steps; per-step sync = 16-wg group barrier.
extern "C" __global__ void __launch_bounds__(128)
rnn_persistent(const float* __restrict__ x, const float* __restrict__ Wk,
               const float* __restrict__ Wr, const float* __restrict__ h0,
               unsigned short* __restrict__ Hbuf0, unsigned short* __restrict__ Hbuf1,
               unsigned int* __restrict__ ctr)
{
  // [col][k] bf16 layout so B-frag (lane holds B[k..k+7][n=lane&15]) is one ds_read_b128
  __shared__ unsigned short Wt[COLS_PER_WG][WT_PITCH];

  const int bid  = blockIdx.x;
  // bijective mapping; members of a row-group share bid%8 -> same XCD (heuristic only)
  const int g    = (bid & 7) + ((bid >> 7) << 3);   // row group 0..15
  const int c    = (bid >> 3) & 15;                 // col group 0..15
  const int row0 = g * ROWS_PER_WG;
  const int col0 = c * COLS_PER_WG;
  const int tid  = threadIdx.x;
  const int wave = tid >> 6;
  const int lane = tid & 63;
  const int m    = lane & 15;   // A-row / C-col / B-n index
  const int quad = lane >> 4;   // k-group selector
  unsigned int* gctr = ctr + g * CTR_PITCH;

  // ---- one-time: stage [Wk;Wr] column slice into LDS as bf16 [col][k] ----
  for (int idx = tid; idx < COLS_PER_WG * K_TOT; idx += 128) {
    int k  = idx >> 5;
    int cl = idx & 31;
    float w = (k < D_SZ) ? Wk[(size_t)k * U_SZ + col0 + cl]
                         : Wr[(size_t)(k - D_SZ) * U_SZ + col0 + cl];
    Wt[cl][k] = f2bf(w);
  }

  // ---- init: write our H slice from h0 (fp32 -> bf16) into buffer 0 ----
  {
    int e  = tid * 4;          // 512 elems / 128 threads
    int rr = e >> 5;
    int cl = e & 31;
    const float* src = h0 + (size_t)(row0 + rr) * U_SZ + col0 + cl;
    unsigned short* dst = Hbuf0 + (size_t)(row0 + rr) * U_SZ + col0 + cl;
    dst[0] = f2bf(src[0]); dst[1] = f2bf(src[1]);
    dst[2] = f2bf(src[2]); dst[3] = f2bf(src[3]);
  }

  // arrive slot 0 (syncthreads also covers the LDS W staging)
  __syncthreads();
  if (tid == 0)
    __hip_atomic_fetch_add(gctr, 1u, __ATOMIC_RELEASE, __HIP_MEMORY_SCOPE_AGENT);

  const int n_l = (wave << 4) + m;                // col within wg tile, 0..31
  const unsigned short* wrow = &Wt[n_l][0];
  const float* xrow = x + (size_t)(row0 + m) * T_STEPS * D_SZ + quad * 8;
  const int colg = col0 + n_l;                    // global U column this lane stores

  unsigned short* bufs[2] = { Hbuf0, Hbuf1 };

  for (int t = 0; t < T_STEPS; ++t) {
    floatx4 acc = {0.f, 0.f, 0.f, 0.f};

    // ---- x @ Wk partial (K=0..255): independent of h, runs BEFORE barrier wait ----
    const float* xp = xrow + (size_t)t * D_SZ;
#pragma unroll
    for (int kb = 0; kb < 8; ++kb) {
      floatx4 lo = *(const floatx4*)(xp + kb * 32);
      floatx4 hi = *(const floatx4*)(xp + kb * 32 + 4);
      union { short8 s; uint4v u; } fu;
      fu.u[0] = pk2(lo[0], lo[1]); fu.u[1] = pk2(lo[2], lo[3]);
      fu.u[2] = pk2(hi[0], hi[1]); fu.u[3] = pk2(hi[2], hi[3]);
      short8 bf = *(const short8*)(wrow + kb * 32 + quad * 8);
      acc = __builtin_amdgcn_mfma_f32_16x16x32_bf16(fu.s, bf, acc, 0, 0, 0);
    }

    // ---- wait: all 16 group members have published H for step t ----
    if (tid == 0) {
      while (__hip_atomic_load(gctr + t, __ATOMIC_RELAXED, __HIP_MEMORY_SCOPE_AGENT) < COLGRPS)
        __builtin_amdgcn_s_sleep(1);
      (void)__hip_atomic_load(gctr + t, __ATOMIC_ACQUIRE, __HIP_MEMORY_SCOPE_AGENT);
    }
    __syncthreads();

    // ---- h @ Wr partial (K=256..767): A-frags straight from global bf16 H ----
    const unsigned short* Hr = bufs[t & 1] + (size_t)(row0 + m) * U_SZ + quad * 8;
#pragma unroll
    for (int kb = 0; kb < 16; ++kb) {
      short8 af = *(const short8*)(Hr + kb * 32);
      short8 bf = *(const short8*)(wrow + D_SZ + kb * 32 + quad * 8);
      acc = __builtin_amdgcn_mfma_f32_16x16x32_bf16(af, bf, acc, 0, 0, 0);
    }

    // ---- tanh (fp32) + store next H slice (C-layout: row=quad*4+i, col=lane&15) ----
    unsigned short* Hw = bufs[(t + 1) & 1];
#pragma unroll
    for (int i = 0; i < 4; ++i) {
      float v = tanhf(acc[i]);
      Hw[(size_t)(row0 + quad * 4 + i) * U_SZ + colg] = f2bf(v);
    }

    // ---- arrive slot t+1 (syncthreads drains stores; release add publishes) ----
    __syncthreads();
    if (tid == 0)
      __hip_atomic_fetch_add(gctr + t + 1, 1u, __ATOMIC_RELEASE, __HIP_MEMORY_SCOPE_AGENT);
  }
}

// out[b][o] = sum_k bf16(hT[b][k]) * Wd[k][o]  (fp32 accumulate)
extern "C" __global__ void __launch_bounds__(256)
out_gemm(const unsigned short* __restrict__ Hf, const float* __restrict__ Wd,
         float* __restrict__ out)
{
  int b = blockIdx.x;
  int o = threadIdx.x;
  const unsigned short* hrow = Hf + (size_t)b * U_SZ;
  float acc = 0.f;
#pragma unroll 8
  for (int k = 0; k < U_SZ; ++k)
    acc += bf2f(hrow[k]) * Wd[(size_t)k * O_SZ + o];
  out[(size_t)b * O_SZ + o] = acc;
}

extern "C" void kernel_launch(void* const* d_in, const int* in_sizes, int n_in,
                              void* d_out, int out_size, void* d_ws, size_t ws_size,
                              hipStream_t stream)
{
  const float* x  = (const float*)d_in[0];   // [B,T,D]
  const float* Wk = (const float*)d_in[1];   // [D,U]
  const float* Wr = (const float*)d_in[2];   // [U,U]
  const float* Wd = (const float*)d_in[3];   // [U,O]
  const float* h0 = (const float*)d_in[4];   // [B,U]
  float* out = (float*)d_out;                // [B,O] fp32

  // ws layout: Hbuf0 | Hbuf1 (bf16 [B][U] each) | barrier counters
  unsigned short* H0 = (unsigned short*)d_ws;
  unsigned short* H1 = H0 + (size_t)B_SZ * U_SZ;
  unsigned int*  ctr = (unsigned int*)((char*)d_ws + (size_t)2 * B_SZ * U_SZ * 2);

  hipMemsetAsync(ctr, 0, (size_t)GROUPS * CTR_PITCH * sizeof(unsigned int), stream);

  void* args[] = { (void*)&x, (void*)&Wk, (void*)&Wr, (void*)&h0,
                   (void*)&H0, (void*)&H1, (void*)&ctr };
  hipLaunchCooperativeKernel((void*)rnn_persistent, dim3(GROUPS * COLGRPS),
                             dim3(128), args, 0, stream);

  // T=1024 even -> final hidden state lands in buffer 0
  out_gemm<<<dim3(B_SZ), dim3(O_SZ), 0, stream>>>(H0, Wd, out);
}

// Round 2
// 4657.044 us; speedup vs baseline: 1.9283x; 1.9283x over previous
//
#include <hip/hip_runtime.h>
#include <hip/hip_bf16.h>

// Problem constants (fixed by the reference)
#define T_STEPS 1024
#define B_SZ 256
#define D_SZ 256
#define U_SZ 512
#define O_SZ 256
#define K_TOT 768            // D + U concatenated K

// Partition: 16 row-groups x 16 col-groups = 256 wgs (1 per CU)
#define ROWS_PER_WG 16       // batch rows per wg == MFMA M
#define COLS_PER_WG 32       // U columns per wg (2 waves x N=16)
#define GROUPS 16            // row groups (barrier groups)
#define COLGRPS 16           // members per barrier group
#define WAVES_PER_GROUP 32   // 16 wgs x 2 waves: wave-granular barrier
#define WT_PITCH 776         // 768 + 8 shorts pad
#define CTR_PITCH 1056       // counter slots per group (>= T+1)

typedef __attribute__((ext_vector_type(8))) short short8;   // MFMA bf16 A/B frag
typedef __attribute__((ext_vector_type(4))) float floatx4;  // MFMA fp32 C/D frag
typedef __attribute__((ext_vector_type(4))) int int4v;      // 16B asm load payload
typedef __attribute__((ext_vector_type(4))) unsigned int uint4v;

__device__ __forceinline__ unsigned short f2bf(float f) {
  union { float f; unsigned int u; } v; v.f = f;
  unsigned int r = v.u + 0x7FFFu + ((v.u >> 16) & 1u);  // RNE
  return (unsigned short)(r >> 16);
}
__device__ __forceinline__ float bf2f(unsigned short s) {
  union { unsigned int u; float f; } v; v.u = ((unsigned int)s) << 16;
  return v.f;
}
__device__ __forceinline__ unsigned int pk2(float a, float b) {
  union { __hip_bfloat162 h; unsigned int u; } cv;
  cv.h = __float22bfloat162_rn(make_float2(a, b));
  return cv.u;
}

// L3-coherent (bypass L1/L2) primitives — no buffer_wbl2/buffer_inv emitted.
__device__ __forceinline__ void store_short_l3(const unsigned short* p, unsigned int v) {
  asm volatile("global_store_short %0, %1, off sc0 sc1"
               :: "v"(p), "v"(v) : "memory");
}
__device__ __forceinline__ int4v load16_l3(const unsigned short* p) {
  int4v r;
  asm volatile("global_load_dwordx4 %0, %1, off sc0 sc1"
               : "=v"(r) : "v"(p) : "memory");
  return r;
}
__device__ __forceinline__ void wait_vm0() {
  asm volatile("s_waitcnt vmcnt(0)" ::: "memory");
}
__device__ __forceinline__ unsigned int load_ctr_l3(const unsigned int* p) {
  unsigned int r;
  asm volatile("global_load_dword %0, %1, off sc0 sc1\n\ts_waitcnt vmcnt(0)"
               : "=v"(r) : "v"(p) : "memory");
  return r;
}

// Persistent RNN kernel. Each wg: rows [16g,16g+16), cols [32c,32c+32).
// W-slice lives in LDS for all T steps; per-step sync = 32-wave group barrier
// through L3-coherent counter, H exchanged via L3 (sc0 sc1), zero cache flushes.
extern "C" __global__ void __launch_bounds__(128)
rnn_persistent(const float* __restrict__ x, const float* __restrict__ Wk,
               const float* __restrict__ Wr, const float* __restrict__ h0,
               unsigned short* __restrict__ Hbuf0, unsigned short* __restrict__ Hbuf1,
               unsigned int* __restrict__ ctr)
{
  __shared__ unsigned short Wt[COLS_PER_WG][WT_PITCH];

  const int bid  = blockIdx.x;
  // members of a row-group share bid%8 -> same XCD (heuristic only)
  const int g    = (bid & 7) + ((bid >> 7) << 3);   // row group 0..15
  const int c    = (bid >> 3) & 15;                 // col group 0..15
  const int row0 = g * ROWS_PER_WG;
  const int col0 = c * COLS_PER_WG;
  const int tid  = threadIdx.x;
  const int wave = tid >> 6;
  const int lane = tid & 63;
  const int m    = lane & 15;   // A-row / C-col / B-n index
  const int quad = lane >> 4;   // k-group selector
  unsigned int* gctr = ctr + g * CTR_PITCH;

  // ---- one-time: stage [Wk;Wr] column slice into LDS as bf16 [col][k] ----
  for (int idx = tid; idx < COLS_PER_WG * K_TOT; idx += 128) {
    int k  = idx >> 5;
    int cl = idx & 31;
    float w = (k < D_SZ) ? Wk[(size_t)k * U_SZ + col0 + cl]
                         : Wr[(size_t)(k - D_SZ) * U_SZ + col0 + cl];
    Wt[cl][k] = f2bf(w);
  }

  // ---- init: write our H slice from h0 (fp32 -> bf16, L3-coherent) ----
  {
    int e  = tid * 4;          // 512 elems / 128 threads
    int rr = e >> 5;
    int cl = e & 31;
    const float* src = h0 + (size_t)(row0 + rr) * U_SZ + col0 + cl;
    const unsigned short* dst = Hbuf0 + (size_t)(row0 + rr) * U_SZ + col0 + cl;
    store_short_l3(dst + 0, f2bf(src[0]));
    store_short_l3(dst + 1, f2bf(src[1]));
    store_short_l3(dst + 2, f2bf(src[2]));
    store_short_l3(dst + 3, f2bf(src[3]));
  }
  wait_vm0();
  __syncthreads();   // Wt visibility across both waves (one-time)
  if (lane == 0)
    __hip_atomic_fetch_add(gctr, 1u, __ATOMIC_RELAXED, __HIP_MEMORY_SCOPE_AGENT);

  const int n_l = (wave << 4) + m;                // col within wg tile, 0..31
  const unsigned short* wrow = &Wt[n_l][0];
  const float* xrow = x + (size_t)(row0 + m) * T_STEPS * D_SZ + quad * 8;
  const int colg = col0 + n_l;                    // global U column this lane stores

  const unsigned short* bufs[2] = { Hbuf0, Hbuf1 };

  for (int t = 0; t < T_STEPS; ++t) {
    floatx4 acc = {0.f, 0.f, 0.f, 0.f};

    // ---- x @ Wk partial (K=0..255): independent of h, runs BEFORE barrier wait ----
    const float* xp = xrow + (size_t)t * D_SZ;
#pragma unroll
    for (int kb = 0; kb < 8; ++kb) {
      floatx4 lo = *(const floatx4*)(xp + kb * 32);
      floatx4 hi = *(const floatx4*)(xp + kb * 32 + 4);
      union { short8 s; uint4v u; } fu;
      fu.u[0] = pk2(lo[0], lo[1]); fu.u[1] = pk2(lo[2], lo[3]);
      fu.u[2] = pk2(hi[0], hi[1]); fu.u[3] = pk2(hi[2], hi[3]);
      short8 bf = *(const short8*)(wrow + kb * 32 + quad * 8);
      acc = __builtin_amdgcn_mfma_f32_16x16x32_bf16(fu.s, bf, acc, 0, 0, 0);
    }

    // ---- wave-granular wait: all 32 group waves published H for step t ----
    {
      const unsigned int* cp = gctr + t;
      for (;;) {
        unsigned int cnt = load_ctr_l3(cp);
        if (cnt >= WAVES_PER_GROUP) break;
        __builtin_amdgcn_s_sleep(1);
      }
    }

    // ---- h @ Wr partial (K=256..767): A-frags from L3-coherent H ----
    const unsigned short* Hr = bufs[t & 1] + (size_t)(row0 + m) * U_SZ + quad * 8;
    int4v araw[16];
#pragma unroll
    for (int kb = 0; kb < 16; ++kb)
      araw[kb] = load16_l3(Hr + kb * 32);
    wait_vm0();
#pragma unroll
    for (int kb = 0; kb < 16; ++kb) {
      union { int4v i; short8 s; } uc; uc.i = araw[kb];
      short8 bf = *(const short8*)(wrow + D_SZ + kb * 32 + quad * 8);
      acc = __builtin_amdgcn_mfma_f32_16x16x32_bf16(uc.s, bf, acc, 0, 0, 0);
    }

    // ---- tanh (fp32) + publish next H sub-tile (L3-coherent) ----
    const unsigned short* Hw = bufs[(t + 1) & 1];
#pragma unroll
    for (int i = 0; i < 4; ++i) {
      float v = tanhf(acc[i]);
      store_short_l3(Hw + (size_t)(row0 + quad * 4 + i) * U_SZ + colg, f2bf(v));
    }
    wait_vm0();   // stores acked at coherent point before arrival
    if (lane == 0)
      __hip_atomic_fetch_add(gctr + t + 1, 1u, __ATOMIC_RELAXED, __HIP_MEMORY_SCOPE_AGENT);
  }
}

// out[b][o] = sum_k bf16(hT[b][k]) * Wd[k][o]  (fp32 accumulate)
extern "C" __global__ void __launch_bounds__(256)
out_gemm(const unsigned short* __restrict__ Hf, const float* __restrict__ Wd,
         float* __restrict__ out)
{
  int b = blockIdx.x;
  int o = threadIdx.x;
  const unsigned short* hrow = Hf + (size_t)b * U_SZ;
  float acc = 0.f;
#pragma unroll 8
  for (int k = 0; k < U_SZ; ++k)
    acc += bf2f(hrow[k]) * Wd[(size_t)k * O_SZ + o];
  out[(size_t)b * O_SZ + o] = acc;
}

extern "C" void kernel_launch(void* const* d_in, const int* in_sizes, int n_in,
                              void* d_out, int out_size, void* d_ws, size_t ws_size,
                              hipStream_t stream)
{
  const float* x  = (const float*)d_in[0];   // [B,T,D]
  const float* Wk = (const float*)d_in[1];   // [D,U]
  const float* Wr = (const float*)d_in[2];   // [U,U]
  const float* Wd = (const float*)d_in[3];   // [U,O]
  const float* h0 = (const float*)d_in[4];   // [B,U]
  float* out = (float*)d_out;                // [B,O] fp32

  // ws layout: Hbuf0 | Hbuf1 (bf16 [B][U] each) | barrier counters
  unsigned short* H0 = (unsigned short*)d_ws;
  unsigned short* H1 = H0 + (size_t)B_SZ * U_SZ;
  unsigned int*  ctr = (unsigned int*)((char*)d_ws + (size_t)2 * B_SZ * U_SZ * 2);

  hipMemsetAsync(ctr, 0, (size_t)GROUPS * CTR_PITCH * sizeof(unsigned int), stream);

  void* args[] = { (void*)&x, (void*)&Wk, (void*)&Wr, (void*)&h0,
                   (void*)&H0, (void*)&H1, (void*)&ctr };
  hipLaunchCooperativeKernel((void*)rnn_persistent, dim3(GROUPS * COLGRPS),
                             dim3(128), args, 0, stream);

  // T=1024 even -> final hidden state lands in buffer 0
  out_gemm<<<dim3(B_SZ), dim3(O_SZ), 0, stream>>>(H0, Wd, out);
}

// Round 3
// 3860.799 us; speedup vs baseline: 2.3260x; 1.2062x over previous
//
#include <hip/hip_runtime.h>
#include <hip/hip_bf16.h>

// Problem constants (fixed by the reference)
#define T_STEPS 1024
#define B_SZ 256
#define D_SZ 256
#define U_SZ 512
#define O_SZ 256
#define K_TOT 768            // D + U concatenated K

// Partition: 16 row-groups x 16 col-groups = 256 wgs (1 per CU)
#define ROWS_PER_WG 16       // batch rows per wg == MFMA M
#define COLS_PER_WG 32       // U columns per wg (2 waves x N=16)
#define GROUPS 16            // row groups (barrier groups)
#define COLGRPS 16           // wgs per barrier group (1 arrival per wg)
#define NUM_WGS 256
#define CTR_PITCH 1056       // counter slots per group (>= T+1)
#define GRID_SLOT (GROUPS * CTR_PITCH)      // one-time grid barrier counter
#define MISM_SLOT (GRID_SLOT + 1)           // XCD-mapping mismatch flag

typedef __attribute__((ext_vector_type(8))) short short8;   // MFMA bf16 A/B frag
typedef __attribute__((ext_vector_type(4))) float floatx4;  // MFMA fp32 C/D frag
typedef __attribute__((ext_vector_type(4))) int int4v;
typedef __attribute__((ext_vector_type(4))) unsigned int uint4v;

__device__ __forceinline__ unsigned short f2bf(float f) {
  union { float f; unsigned int u; } v; v.f = f;
  unsigned int r = v.u + 0x7FFFu + ((v.u >> 16) & 1u);  // RNE
  return (unsigned short)(r >> 16);
}
__device__ __forceinline__ float bf2f(unsigned short s) {
  union { unsigned int u; float f; } v; v.u = ((unsigned int)s) << 16;
  return v.f;
}
__device__ __forceinline__ unsigned int pk2(float a, float b) {
  union { __hip_bfloat162 h; unsigned int u; } cv;
  cv.h = __float22bfloat162_rn(make_float2(a, b));
  return cv.u;
}
__device__ __forceinline__ void wait_vm0() {
  asm volatile("s_waitcnt vmcnt(0)" ::: "memory");
}

// FAST = sync group verified XCD-local: coherence point = that XCD's L2.
//   stores: plain (L1 is write-through -> lands in L2)
//   loads:  sc0 (bypass L1, read L2)
//   atomic: plain global_atomic_add (executes at local L2)
// !FAST = device-wide: sc0 sc1 (bypass L1+L2, MALL) + agent-scope atomics.
template <bool FAST>
__device__ __forceinline__ void store_h(const unsigned short* p, unsigned int v) {
  if constexpr (FAST)
    asm volatile("global_store_short %0, %1, off" :: "v"(p), "v"(v) : "memory");
  else
    asm volatile("global_store_short %0, %1, off sc0 sc1" :: "v"(p), "v"(v) : "memory");
}
template <bool FAST>
__device__ __forceinline__ int4v load16(const unsigned short* p) {
  int4v r;
  if constexpr (FAST)
    asm volatile("global_load_dwordx4 %0, %1, off sc0" : "=v"(r) : "v"(p) : "memory");
  else
    asm volatile("global_load_dwordx4 %0, %1, off sc0 sc1" : "=v"(r) : "v"(p) : "memory");
  return r;
}
template <bool FAST>
__device__ __forceinline__ unsigned int load_ctr(const unsigned int* p) {
  unsigned int r;
  if constexpr (FAST)
    asm volatile("global_load_dword %0, %1, off sc0\n\ts_waitcnt vmcnt(0)"
                 : "=v"(r) : "v"(p) : "memory");
  else
    asm volatile("global_load_dword %0, %1, off sc0 sc1\n\ts_waitcnt vmcnt(0)"
                 : "=v"(r) : "v"(p) : "memory");
  return r;
}
template <bool FAST>
__device__ __forceinline__ void arrive(unsigned int* p) {
  if constexpr (FAST)
    asm volatile("global_atomic_add %0, %1, off" :: "v"(p), "v"(1u) : "memory");
  else
    __hip_atomic_fetch_add(p, 1u, __ATOMIC_RELAXED, __HIP_MEMORY_SCOPE_AGENT);
}

template <bool FAST>
__device__ __forceinline__ void run_loop(const float* xrow, const unsigned short* wq,
                                         const unsigned short* Hb0, const unsigned short* Hb1,
                                         unsigned int* gctr, int row0, int colg,
                                         int m, int quad, int tid)
{
  const unsigned short* bufs[2] = { Hb0, Hb1 };
  for (int t = 0; t < T_STEPS; ++t) {
    floatx4 acc = {0.f, 0.f, 0.f, 0.f};

    // x @ Wk partial (K=0..255): independent of h, runs BEFORE barrier wait
    const float* xp = xrow + (size_t)t * D_SZ;
#pragma unroll
    for (int kb = 0; kb < 8; ++kb) {
      floatx4 lo = *(const floatx4*)(xp + kb * 32);
      floatx4 hi = *(const floatx4*)(xp + kb * 32 + 4);
      union { short8 s; uint4v u; } fu;
      fu.u[0] = pk2(lo[0], lo[1]); fu.u[1] = pk2(lo[2], lo[3]);
      fu.u[2] = pk2(hi[0], hi[1]); fu.u[3] = pk2(hi[2], hi[3]);
      short8 bfr = *(const short8*)(wq + kb * 1024);
      acc = __builtin_amdgcn_mfma_f32_16x16x32_bf16(fu.s, bfr, acc, 0, 0, 0);
    }

    // wait: all 16 group wgs published H for step t
    {
      const unsigned int* cp = gctr + t;
      for (;;) {
        if (load_ctr<FAST>(cp) >= COLGRPS) break;
        __builtin_amdgcn_s_sleep(1);
      }
    }

    // h @ Wr partial (K=256..767)
    const unsigned short* Hr = bufs[t & 1] + (size_t)(row0 + m) * U_SZ + quad * 8;
    int4v araw[16];
#pragma unroll
    for (int kb = 0; kb < 16; ++kb)
      araw[kb] = load16<FAST>(Hr + kb * 32);
    wait_vm0();
#pragma unroll
    for (int kb = 0; kb < 16; ++kb) {
      union { int4v i; short8 s; } uc; uc.i = araw[kb];
      short8 bfr = *(const short8*)(wq + (kb + 8) * 1024);
      acc = __builtin_amdgcn_mfma_f32_16x16x32_bf16(uc.s, bfr, acc, 0, 0, 0);
    }

    // tanh + publish next H sub-tile
    const unsigned short* Hw = bufs[(t + 1) & 1];
#pragma unroll
    for (int i = 0; i < 4; ++i) {
      float v = tanhf(acc[i]);
      store_h<FAST>(Hw + (size_t)(row0 + quad * 4 + i) * U_SZ + colg, f2bf(v));
    }
    wait_vm0();        // stores acked at the coherence point
    __syncthreads();   // both waves done -> one arrival per wg
    if (tid == 0) arrive<FAST>(gctr + t + 1);
  }
}

extern "C" __global__ void __launch_bounds__(128)
rnn_persistent(const float* __restrict__ x, const float* __restrict__ Wk,
               const float* __restrict__ Wr, const float* __restrict__ h0,
               unsigned short* __restrict__ Hbuf0, unsigned short* __restrict__ Hbuf1,
               unsigned int* __restrict__ ctr)
{
  // Blocked conflict-free layout: short index ((kb*4+quad)*32 + col)*8 + k8,
  // k = kb*32 + quad*8 + k8. A wave's b128 frag reads are 256B-contiguous.
  __shared__ unsigned short Wt[K_TOT * COLS_PER_WG];

  const int bid  = blockIdx.x;
  // group members share bid&7; with bid%8 XCD round-robin -> one XCD per group
  const int g    = (bid & 7) * 2 + (bid >> 7);      // row group 0..15
  const int c    = (bid >> 3) & 15;                 // col group 0..15
  const int row0 = g * ROWS_PER_WG;
  const int col0 = c * COLS_PER_WG;
  const int tid  = threadIdx.x;
  const int wave = tid >> 6;
  const int lane = tid & 63;
  const int m    = lane & 15;
  const int quad = lane >> 4;
  unsigned int* gctr = ctr + g * CTR_PITCH;

  // ---- one-time: stage [Wk;Wr] column slice into LDS (blocked layout) ----
  for (int idx = tid; idx < COLS_PER_WG * K_TOT; idx += 128) {
    int k  = idx >> 5;
    int cl = idx & 31;
    float w = (k < D_SZ) ? Wk[(size_t)k * U_SZ + col0 + cl]
                         : Wr[(size_t)(k - D_SZ) * U_SZ + col0 + cl];
    int off = (((k >> 5) * 4 + ((k >> 3) & 3)) * 32 + cl) * 8 + (k & 7);
    Wt[off] = f2bf(w);
  }

  // ---- verify XCD mapping, one-time grid barrier, uniform path decision ----
  unsigned int xcc;
  asm volatile("s_getreg_b32 %0, hwreg(HW_REG_XCC_ID)" : "=s"(xcc));
  xcc &= 0xF;
  if (tid == 0 && xcc != (unsigned int)(bid & 7))
    __hip_atomic_fetch_or(ctr + MISM_SLOT, 1u, __ATOMIC_RELAXED, __HIP_MEMORY_SCOPE_AGENT);
  wait_vm0();
  __syncthreads();
  if (tid == 0)
    __hip_atomic_fetch_add(ctr + GRID_SLOT, 1u, __ATOMIC_RELAXED, __HIP_MEMORY_SCOPE_AGENT);
  if (tid == 0) {
    while (load_ctr<false>(ctr + GRID_SLOT) < NUM_WGS)
      __builtin_amdgcn_s_sleep(4);
  }
  __syncthreads();
  const bool fast = (load_ctr<false>(ctr + MISM_SLOT) == 0);

  // ---- init: publish h0 slice (fp32 -> bf16) into buffer 0 ----
  {
    int e  = tid * 4;
    int rr = e >> 5;
    int cl = e & 31;
    const float* src = h0 + (size_t)(row0 + rr) * U_SZ + col0 + cl;
    const unsigned short* dst = Hbuf0 + (size_t)(row0 + rr) * U_SZ + col0 + cl;
    if (fast) {
      store_h<true>(dst + 0, f2bf(src[0])); store_h<true>(dst + 1, f2bf(src[1]));
      store_h<true>(dst + 2, f2bf(src[2])); store_h<true>(dst + 3, f2bf(src[3]));
    } else {
      store_h<false>(dst + 0, f2bf(src[0])); store_h<false>(dst + 1, f2bf(src[1]));
      store_h<false>(dst + 2, f2bf(src[2])); store_h<false>(dst + 3, f2bf(src[3]));
    }
  }
  wait_vm0();
  __syncthreads();   // also covers Wt staging visibility
  if (tid == 0) {
    if (fast) arrive<true>(gctr);
    else      arrive<false>(gctr);
  }

  const int n_l  = (wave << 4) + m;
  const int colg = col0 + n_l;
  const unsigned short* wq = &Wt[quad * 256 + n_l * 8];
  const float* xrow = x + (size_t)(row0 + m) * T_STEPS * D_SZ + quad * 8;

  if (fast)
    run_loop<true>(xrow, wq, Hbuf0, Hbuf1, gctr, row0, colg, m, quad, tid);
  else
    run_loop<false>(xrow, wq, Hbuf0, Hbuf1, gctr, row0, colg, m, quad, tid);
}

// out[b][o] = sum_k bf16(hT[b][k]) * Wd[k][o]  (fp32 accumulate)
extern "C" __global__ void __launch_bounds__(256)
out_gemm(const unsigned short* __restrict__ Hf, const float* __restrict__ Wd,
         float* __restrict__ out)
{
  int b = blockIdx.x;
  int o = threadIdx.x;
  const unsigned short* hrow = Hf + (size_t)b * U_SZ;
  float acc = 0.f;
#pragma unroll 8
  for (int k = 0; k < U_SZ; ++k)
    acc += bf2f(hrow[k]) * Wd[(size_t)k * O_SZ + o];
  out[(size_t)b * O_SZ + o] = acc;
}

extern "C" void kernel_launch(void* const* d_in, const int* in_sizes, int n_in,
                              void* d_out, int out_size, void* d_ws, size_t ws_size,
                              hipStream_t stream)
{
  const float* x  = (const float*)d_in[0];   // [B,T,D]
  const float* Wk = (const float*)d_in[1];   // [D,U]
  const float* Wr = (const float*)d_in[2];   // [U,U]
  const float* Wd = (const float*)d_in[3];   // [U,O]
  const float* h0 = (const float*)d_in[4];   // [B,U]
  float* out = (float*)d_out;                // [B,O] fp32

  // ws layout: Hbuf0 | Hbuf1 (bf16 [B][U] each) | barrier counters
  unsigned short* H0 = (unsigned short*)d_ws;
  unsigned short* H1 = H0 + (size_t)B_SZ * U_SZ;
  unsigned int*  ctr = (unsigned int*)((char*)d_ws + (size_t)2 * B_SZ * U_SZ * 2);

  hipMemsetAsync(ctr, 0, (size_t)(GROUPS * CTR_PITCH + 64) * sizeof(unsigned int), stream);

  void* args[] = { (void*)&x, (void*)&Wk, (void*)&Wr, (void*)&h0,
                   (void*)&H0, (void*)&H1, (void*)&ctr };
  hipLaunchCooperativeKernel((void*)rnn_persistent, dim3(NUM_WGS),
                             dim3(128), args, 0, stream);

  // T=1024 even -> final hidden state lands in buffer 0
  out_gemm<<<dim3(B_SZ), dim3(O_SZ), 0, stream>>>(H0, Wd, out);
}